// Round 14
// baseline (1732.431 us; speedup 1.0000x reference)
//
#include <hip/hip_runtime.h>

// Problem constants
#define BB 2048   // batch
#define TT 128    // timesteps
#define VV 25     // input features
#define HH 512    // hidden
#define NC 100    // classes

typedef __attribute__((ext_vector_type(8))) _Float16 half8;
typedef __attribute__((ext_vector_type(4))) float f32x4;

__device__ __forceinline__ float fsigmoid(float x) { return 1.0f / (1.0f + __expf(-x)); }
__device__ __forceinline__ float ftanh(float x) {
    float e = __expf(2.0f * x);
    return 1.0f - 2.0f / (e + 1.0f);
}

// ---- prep: weights -> MFMA-fragment-native fp16 layout ----
// WT[kq][n] : 16B group = fp16(W[n][kq*8 .. kq*8+7])  (kq 0..63 = W_hh,
// 64..67 = W_ih zero-padded to K=32). B-frag load for K32 chunk cc:
// lane(col,quad) reads WT[cc*4+quad][n0+col] -> 4 x 256B segments.
__global__ __launch_bounds__(256) void prep_whh_t(const float* __restrict__ W,
                                                  _Float16* __restrict__ WT) {
    int i = blockIdx.x * 256 + threadIdx.x;   // 2048 n x 64 kq, grid 512
    int n = i & 2047, kq = i >> 11;
    half8 h8;
    #pragma unroll
    for (int j = 0; j < 8; ++j) h8[j] = (_Float16)W[(size_t)n * HH + kq * 8 + j];  // RNE cvt
    ((half8*)WT)[(size_t)kq * 2048 + n] = h8;
}

__global__ __launch_bounds__(256) void prep_wih_t(const float* __restrict__ W,
                                                  _Float16* __restrict__ WT) {
    int i = blockIdx.x * 256 + threadIdx.x;   // 2048 n x 4 kq, grid 32
    int n = i & 2047, kq4 = i >> 11;
    half8 h8;
    #pragma unroll
    for (int j = 0; j < 8; ++j) {
        int k = kq4 * 8 + j;
        h8[j] = (k < VV) ? (_Float16)W[(size_t)n * VV + k] : (_Float16)0.0f;
    }
    ((half8*)WT)[(size_t)(64 + kq4) * 2048 + n] = h8;
}

// One LSTM timestep — r13 structure with DOUBLE B-reuse: wave tile
// 4 m-tiles x 4 gates (each B fragment feeds 4 MFMAs, not 2), so the
// B request stream halves (142 -> 71 MB/step) and per-chunk MFMA issue
// density doubles (16 back-to-back MFMAs).
// Block = 128 thr (2 waves) = 64 batch x 32 j (x4 gates); wave w = wn
// (16-j half), each wave covers all 64 batch rows (tm=0..3).
// Grid (32,16) = 512 blocks = 2 blocks/CU, 4 waves/CU (1 wave/SIMD; r4 vs
// r6 showed TLP is not the limiter when B-bound). acc[4][4] = 64 VGPR,
// total ~160 << 512 budget at this occupancy.
// B-frags stream register-direct from L2 (frag-native WT); A (h fp16) via
// double-buffered LDS, one barrier per K64. Launch-per-step (launch = the
// cheap global barrier; r9/r11: in-kernel cross-XCD exchange costs more).
__global__ __launch_bounds__(128) void lstm_step(
    const float* __restrict__ msg, int t,
    const _Float16* __restrict__ WT,
    const float* __restrict__ b_ih, const float* __restrict__ b_hh,
    const _Float16* __restrict__ hin, _Float16* __restrict__ hout,
    float* __restrict__ c)
{
    const int b0 = blockIdx.x * 64;
    const int j0 = blockIdx.y * 32;
    const int tid = threadIdx.x;
    const int lane = tid & 63;
    const int wn = tid >> 6;            // j-half
    const int col = lane & 15, quad = lane >> 4;
    const int jj = j0 + wn * 16 + col;

    // [buf][row][k]; row stride 72 halves (144B, 16B-aligned): frag b128
    // reads conflict-free (r13-proven). 18.4 KB total.
    __shared__ _Float16 Abuf[2][64][72];

    f32x4 acc[4][4];   // [tm][gate]
    #pragma unroll
    for (int g = 0; g < 4; ++g) {
        float bias = b_ih[g * HH + jj] + b_hh[g * HH + jj];
        f32x4 bv = {bias, bias, bias, bias};
        #pragma unroll
        for (int tm = 0; tm < 4; ++tm) acc[tm][g] = bv;
    }

    // A staging: 64 rows x 64 k / 128 thr -> 32 halves (4 x half8) each.
    // thread -> (row = tid>>1, 32-k segment = (tid&1)*32)
    const int arow = tid >> 1, aseg = (tid & 1) << 5;
    const _Float16* aph = hin + (size_t)(b0 + arow) * HH + aseg;

    const half8* WT8 = (const half8*)WT;
    int bidx[4];
    #pragma unroll
    for (int g = 0; g < 4; ++g) bidx[g] = quad * 2048 + g * HH + j0 + wn * 16 + col;

    half8 Bs[2][4];        // B double-buffer regs (K32-chunk parity)
    half8 ra[4];           // staged A regs (next K64 chunk)

    // ---- prologue: K64 chunk0 -> LDS buf0; chunk1 -> ra; B chunks 0,1 ----
    #pragma unroll
    for (int i = 0; i < 4; ++i) ra[i] = *(const half8*)(aph + i * 8);
    #pragma unroll
    for (int g = 0; g < 4; ++g) Bs[0][g] = WT8[bidx[g]];
    #pragma unroll
    for (int i = 0; i < 4; ++i) *(half8*)&Abuf[0][arow][aseg + i * 8] = ra[i];
    #pragma unroll
    for (int i = 0; i < 4; ++i) ra[i] = *(const half8*)(aph + 64 + i * 8);
    #pragma unroll
    for (int g = 0; g < 4; ++g) Bs[1][g] = WT8[8192 + bidx[g]];
    __syncthreads();

    float xv[16];                        // msg tail values
    const int xrow = tid >> 1, xk0 = (tid & 1) << 4;

    for (int it = 0; it < 8; ++it) {
        const int buf = it & 1;
        #pragma unroll
        for (int kk = 0; kk < 2; ++kk) {
            const int cchunk = it * 2 + kk;  // K32 chunk 0..15
            const int p = cchunk & 1;
            half8 ahf[4];
            #pragma unroll
            for (int tm = 0; tm < 4; ++tm)
                ahf[tm] = *(const half8*)&Abuf[buf][tm * 16 + col][kk * 32 + quad * 8];
            #pragma unroll
            for (int tm = 0; tm < 4; ++tm)
                #pragma unroll
                for (int g = 0; g < 4; ++g)
                    acc[tm][g] = __builtin_amdgcn_mfma_f32_16x16x32_f16(ahf[tm], Bs[p][g], acc[tm][g], 0, 0, 0);
            // prefetch B chunk+2 into slot just consumed (chunk 16 = Wih tail)
            if (cchunk + 2 <= 16) {
                const int ix = (cchunk + 2) * 8192;
                #pragma unroll
                for (int g = 0; g < 4; ++g) Bs[p][g] = WT8[ix + bidx[g]];
            }
        }
        if (it < 7) {
            #pragma unroll
            for (int i = 0; i < 4; ++i)
                *(half8*)&Abuf[buf ^ 1][arow][aseg + i * 8] = ra[i];   // ra = chunk it+1
            if (it < 6) {
                const int kt = (it + 2) * 64;
                #pragma unroll
                for (int i = 0; i < 4; ++i) ra[i] = *(const half8*)(aph + kt + i * 8);
            } else {
                // it==6: load msg tail (K=25 padded to 32): row=tid>>1, 16 k's each
                const size_t mb = ((size_t)(b0 + xrow) * TT + t) * VV;
                #pragma unroll
                for (int i = 0; i < 16; ++i) {
                    int k = xk0 + i;
                    xv[i] = (k < VV) ? msg[mb + k] : 0.0f;
                }
            }
        } else {
            // it==7: convert + stage x-tail into buf0 (buf0 last read at it==6)
            half8 xh0, xh1;
            #pragma unroll
            for (int i = 0; i < 8; ++i) { xh0[i] = (_Float16)xv[i]; xh1[i] = (_Float16)xv[8 + i]; }
            *(half8*)&Abuf[0][xrow][xk0]     = xh0;
            *(half8*)&Abuf[0][xrow][xk0 + 8] = xh1;
        }
        __syncthreads();
    }

    // ---- x-projection tail: chunk 16 (K=32), buf0, B slot 0 ----
    {
        half8 ahf[4];
        #pragma unroll
        for (int tm = 0; tm < 4; ++tm)
            ahf[tm] = *(const half8*)&Abuf[0][tm * 16 + col][quad * 8];
        #pragma unroll
        for (int tm = 0; tm < 4; ++tm)
            #pragma unroll
            for (int g = 0; g < 4; ++g)
                acc[tm][g] = __builtin_amdgcn_mfma_f32_16x16x32_f16(ahf[tm], Bs[0][g], acc[tm][g], 0, 0, 0);
    }

    // ---- cell update; h written as a single fp16 plane ----
    // C/D layout: col=lane&15 (=n), row=quad*4+reg  [m89]
    #pragma unroll
    for (int tm = 0; tm < 4; ++tm) {
        #pragma unroll
        for (int reg = 0; reg < 4; ++reg) {
            int b = b0 + tm * 16 + quad * 4 + reg;
            size_t idx = (size_t)b * HH + jj;
            float i_ = fsigmoid(acc[tm][0][reg]);
            float f_ = fsigmoid(acc[tm][1][reg]);
            float g_ = ftanh(acc[tm][2][reg]);
            float o_ = fsigmoid(acc[tm][3][reg]);
            float cn = f_ * c[idx] + i_ * g_;
            c[idx] = cn;
            hout[idx] = (_Float16)(o_ * ftanh(cn));
        }
    }
}

// out[b, cls] = dot(h, W_fc[cls]) + b_fc[cls]. 4 rows/block.
__global__ __launch_bounds__(256) void fc_kernel(
    const _Float16* __restrict__ h, const float* __restrict__ W_fc,
    const float* __restrict__ b_fc, float* __restrict__ out)
{
    __shared__ float hs[4][HH];
    const int b0 = blockIdx.x * 4;
    for (int i = threadIdx.x; i < 4 * HH; i += 256) {
        int r = i >> 9, k = i & 511;
        hs[r][k] = (float)h[(size_t)(b0 + r) * HH + k];
    }
    __syncthreads();
    const int tid = threadIdx.x;
    if (tid < 2 * NC) {
        int r = tid / NC, cls = tid % NC;
        const float4* wv = (const float4*)(W_fc + (size_t)cls * HH);
        const float4* h0 = (const float4*)hs[r];
        const float4* h1 = (const float4*)hs[r + 2];
        float s0 = 0.0f, s1 = 0.0f;
        #pragma unroll 4
        for (int k = 0; k < HH / 4; ++k) {
            float4 ww = wv[k];
            float4 a0 = h0[k], a1 = h1[k];
            s0 += a0.x * ww.x + a0.y * ww.y + a0.z * ww.z + a0.w * ww.w;
            s1 += a1.x * ww.x + a1.y * ww.y + a1.z * ww.z + a1.w * ww.w;
        }
        out[(size_t)(b0 + r) * NC + cls] = s0 + b_fc[cls];
        out[(size_t)(b0 + r + 2) * NC + cls] = s1 + b_fc[cls];
    }
}

extern "C" void kernel_launch(void* const* d_in, const int* in_sizes, int n_in,
                              void* d_out, int out_size, void* d_ws, size_t ws_size,
                              hipStream_t stream) {
    const float* msg  = (const float*)d_in[0];
    const float* W_ih = (const float*)d_in[1];
    const float* W_hh = (const float*)d_in[2];
    const float* b_ih = (const float*)d_in[3];
    const float* b_hh = (const float*)d_in[4];
    const float* W_fc = (const float*)d_in[5];
    const float* b_fc = (const float*)d_in[6];
    float* out = (float*)d_out;

    // ws: c(4MB) | h0 h1 (fp16, 2MB ea) | WT (fp16, 2.23MB) = 10.2MB
    float*    c  = (float*)d_ws;
    _Float16* h0 = (_Float16*)(c + (size_t)BB * HH);
    _Float16* h1 = h0 + (size_t)BB * HH;
    _Float16* WT = h1 + (size_t)BB * HH;

    // zero c + h0 (contiguous 6 MB); h1 fully written at t=0
    hipMemsetAsync(d_ws, 0, (size_t)BB * HH * 4 + (size_t)BB * HH * 2, stream);

    prep_whh_t<<<512, 256, 0, stream>>>(W_hh, WT);
    prep_wih_t<<<32, 256, 0, stream>>>(W_ih, WT);

    _Float16 *hin = h0, *hout = h1;
    for (int t = 0; t < TT; ++t) {
        lstm_step<<<dim3(BB / 64, HH / 32), 128, 0, stream>>>(
            msg, t, WT, b_ih, b_hh, hin, hout, c);
        _Float16* tmp = hin; hin = hout; hout = tmp;
    }
    fc_kernel<<<BB / 4, 256, 0, stream>>>(hin, W_fc, b_fc, out);
}